// Round 1
// baseline (402.292 us; speedup 1.0000x reference)
//
#include <hip/hip_runtime.h>
#include <hip/hip_bf16.h>
#include <stdint.h>

#define BB 16
#define TT 1024
#define DD 256

typedef __attribute__((ext_vector_type(8))) short short8;
typedef __attribute__((ext_vector_type(4))) float floatx4;

__device__ __forceinline__ unsigned short f2bf(float f) {
    union { float f; unsigned int u; } c; c.f = f;
    unsigned int u = c.u;
    // round-to-nearest-even bf16 truncation (inputs are finite gaussians, no NaN)
    unsigned int r = (u + 0x7FFFu + ((u >> 16) & 1u)) >> 16;
    return (unsigned short)r;
}

// One 64-lane wave per row of z (D=256 -> 4 floats/lane).
// Also zeroes the global double accumulator (block 0 / thread 0).
__global__ __launch_bounds__(256) void prep_kernel(
    const float* __restrict__ z, float* __restrict__ z2,
    unsigned short* __restrict__ zb, double* __restrict__ acc) {
    if (blockIdx.x == 0 && threadIdx.x == 0) *acc = 0.0;
    const int lane = threadIdx.x & 63;
    const int row  = blockIdx.x * 4 + (threadIdx.x >> 6);   // [0, BB*TT)
    const float4 v = ((const float4*)(z + (size_t)row * DD))[lane];
    float ss = v.x * v.x + v.y * v.y + v.z * v.z + v.w * v.w;
    ushort4 o;
    o.x = f2bf(v.x); o.y = f2bf(v.y); o.z = f2bf(v.z); o.w = f2bf(v.w);
    ((ushort4*)(zb + (size_t)row * DD))[lane] = o;
#pragma unroll
    for (int off = 32; off > 0; off >>= 1) ss += __shfl_down(ss, off);
    if (lane == 0) z2[row] = ss;
}

// Fused: per-wave 32x32 (t,s) tile.
//  - Gram tile via 2x2 grid of mfma_f32_16x16x32_bf16 over D=256 (8 k-steps)
//  - stream gt_dT tile (float4/pair), w = exp2(-sum ck*d^2), accumulate
//    w * (z2[t] + z2[s] - 2*G[t,s]) into per-lane fp32 partial.
// A-frag: lane holds z[t0 + (lane&15)][kstep*32 + (lane>>4)*8 .. +7]  (16B)
// B-frag: identical pattern from row s0 + (lane&15)  (B = Z^T, row-major Z)
// C/D:    G[t0 + (lane>>4)*4 + r][s0 + (lane&15)]   [verified layout, m89/m91]
__global__ __launch_bounds__(256) void patch_kernel(
    const unsigned short* __restrict__ zb, const float* __restrict__ z2,
    const float* __restrict__ gt, const float* __restrict__ sigma,
    double* __restrict__ acc) {
    const float LOG2E = 1.4426950408889634f;
    const float s0v = sigma[0], s1v = sigma[1], s2v = sigma[2], s3v = sigma[3];
    const float c0 = LOG2E * 0.5f / (s0v * s0v);
    const float c1 = LOG2E * 0.5f / (s1v * s1v);
    const float c2 = LOG2E * 0.5f / (s2v * s2v);
    const float c3 = LOG2E * 0.5f / (s3v * s3v);

    const int tid  = threadIdx.x;
    const int lane = tid & 63;
    const int quad = lane >> 4;
    const int m    = lane & 15;
    const int wid  = blockIdx.x * 4 + (tid >> 6);
    const int nW   = gridDim.x * 4;
    const int nTiles = BB * (TT / 32) * (TT / 32);   // 16384

    float partial = 0.f;

    for (int tile = wid; tile < nTiles; tile += nW) {
        const int b   = tile >> 10;        // / (32*32)
        const int rem = tile & 1023;
        const int t0  = (rem >> 5) << 5;
        const int s0  = (rem & 31) << 5;

        const unsigned short* zrow = zb + (size_t)b * TT * DD;
        const short8* at0 = (const short8*)(zrow + (t0 + m) * DD + quad * 8);
        const short8* at1 = (const short8*)(zrow + (t0 + 16 + m) * DD + quad * 8);
        const short8* bs0 = (const short8*)(zrow + (s0 + m) * DD + quad * 8);
        const short8* bs1 = (const short8*)(zrow + (s0 + 16 + m) * DD + quad * 8);

        floatx4 g00 = {0.f, 0.f, 0.f, 0.f};
        floatx4 g01 = {0.f, 0.f, 0.f, 0.f};
        floatx4 g10 = {0.f, 0.f, 0.f, 0.f};
        floatx4 g11 = {0.f, 0.f, 0.f, 0.f};
#pragma unroll
        for (int k = 0; k < 8; ++k) {
            // k-step advances 32 bf16 = 4 short8's
            const short8 a0 = at0[k * 4];
            const short8 a1 = at1[k * 4];
            const short8 b0 = bs0[k * 4];
            const short8 b1 = bs1[k * 4];
            g00 = __builtin_amdgcn_mfma_f32_16x16x32_bf16(a0, b0, g00, 0, 0, 0);
            g01 = __builtin_amdgcn_mfma_f32_16x16x32_bf16(a0, b1, g01, 0, 0, 0);
            g10 = __builtin_amdgcn_mfma_f32_16x16x32_bf16(a1, b0, g10, 0, 0, 0);
            g11 = __builtin_amdgcn_mfma_f32_16x16x32_bf16(a1, b1, g11, 0, 0, 0);
        }

        const float* z2b  = z2 + b * TT;
        const float  z2s0 = z2b[s0 + m];
        const float  z2s1 = z2b[s0 + 16 + m];
        const float* gtb  = gt + (size_t)b * TT * TT * 4;
        const int    tq   = t0 + quad * 4;

#pragma unroll
        for (int r = 0; r < 4; ++r) {
            const float z2t0 = z2b[tq + r];
            const float z2t1 = z2b[tq + 16 + r];
            {   // (tb=0, sb=0)
                const float4 d = *(const float4*)(gtb + ((size_t)(tq + r) * TT + (s0 + m)) * 4);
                const float kern = c0 * d.x * d.x + c1 * d.y * d.y + c2 * d.z * d.z + c3 * d.w * d.w;
                partial += exp2f(-kern) * (z2t0 + z2s0 - 2.f * g00[r]);
            }
            {   // (tb=0, sb=1)
                const float4 d = *(const float4*)(gtb + ((size_t)(tq + r) * TT + (s0 + 16 + m)) * 4);
                const float kern = c0 * d.x * d.x + c1 * d.y * d.y + c2 * d.z * d.z + c3 * d.w * d.w;
                partial += exp2f(-kern) * (z2t0 + z2s1 - 2.f * g01[r]);
            }
            {   // (tb=1, sb=0)
                const float4 d = *(const float4*)(gtb + ((size_t)(tq + 16 + r) * TT + (s0 + m)) * 4);
                const float kern = c0 * d.x * d.x + c1 * d.y * d.y + c2 * d.z * d.z + c3 * d.w * d.w;
                partial += exp2f(-kern) * (z2t1 + z2s0 - 2.f * g10[r]);
            }
            {   // (tb=1, sb=1)
                const float4 d = *(const float4*)(gtb + ((size_t)(tq + 16 + r) * TT + (s0 + 16 + m)) * 4);
                const float kern = c0 * d.x * d.x + c1 * d.y * d.y + c2 * d.z * d.z + c3 * d.w * d.w;
                partial += exp2f(-kern) * (z2t1 + z2s1 - 2.f * g11[r]);
            }
        }
    }

    // wave reduce (64 lanes) then block reduce -> one double atomic per block
#pragma unroll
    for (int off = 32; off > 0; off >>= 1) partial += __shfl_down(partial, off);
    __shared__ float red[4];
    if (lane == 0) red[tid >> 6] = partial;
    __syncthreads();
    if (tid == 0) atomicAdd(acc, (double)(red[0] + red[1] + red[2] + red[3]));
}

__global__ void finalize_kernel(const double* __restrict__ acc, float* __restrict__ out) {
    out[0] = (float)(*acc * (1.0 / ((double)BB * (double)TT * (double)TT)));
}

extern "C" void kernel_launch(void* const* d_in, const int* in_sizes, int n_in,
                              void* d_out, int out_size, void* d_ws, size_t ws_size,
                              hipStream_t stream) {
    const float* z     = (const float*)d_in[0];   // [16,1024,256]
    const float* gt    = (const float*)d_in[1];   // [16,1024,1024,4]
    const float* sigma = (const float*)d_in[2];   // [4]
    float* out = (float*)d_out;

    // ws layout: [0,8)=double acc | 64: z2 (B*T floats = 64 KB) | 65600: zb (B*T*D bf16 = 8 MB)
    char* ws = (char*)d_ws;
    double* acc        = (double*)ws;
    float* z2          = (float*)(ws + 64);
    unsigned short* zb = (unsigned short*)(ws + 64 + (size_t)BB * TT * sizeof(float));

    prep_kernel<<<BB * TT / 4, 256, 0, stream>>>(z, z2, zb, acc);
    patch_kernel<<<2048, 256, 0, stream>>>(zb, z2, gt, sigma, acc);
    finalize_kernel<<<1, 1, 0, stream>>>(acc, out);
}